// Round 16
// baseline (478.514 us; speedup 1.0000x reference)
//
#include <hip/hip_runtime.h>
#include <hip/hip_bf16.h>

// Dense transformer forward, round 30: head-pooling fusion on the R29
// structure (476.8us measured). Final-layer oproj_ffn reduces its LN2 output
// over each wave's 16 nodes (4 shfl_xor per channel) and writes per-wave
// 128-float partials to pool_part[blockIdx*4+wave] (1MB f32 in the dead xb
// workspace slot; each slot written once -> no atomics/zeroing). head now
// reads 1MB of partials instead of re-reading 8.4MB of h. Gated by a
// wave-uniform pool_part != nullptr (null for layers 0-4). Pool uses
// pre-rounding f32 (closer to reference than bf16-rounded sums).
// attn / gemm_in / prep byte-identical to R29. B=64 x L=512, D=128, H=8,
// LAYERS=6, FF=512, OUT=10.

#define NROWS (64 * 512)
#define NLAYER 6

typedef __bf16 bf16x8 __attribute__((ext_vector_type(8)));
typedef float  f32x4  __attribute__((ext_vector_type(4)));
typedef float  f32x16 __attribute__((ext_vector_type(16)));

#define QSCALE 0.36067376022224085f   // 1/sqrt(16) * log2(e)

#if defined(__has_builtin)
#  if __has_builtin(__builtin_amdgcn_exp2f)
#    define FAST_EXP2(x) __builtin_amdgcn_exp2f(x)
#  endif
#endif
#ifndef FAST_EXP2
#  define FAST_EXP2(x) __expf((x) * 0.6931471805599453f)
#endif

__device__ __forceinline__ __hip_bfloat16 f2bf(float x) { return __float2bfloat16(x); }

__device__ __forceinline__ __hip_bfloat16 bf_rta(float a) {
  union { float f; unsigned u; } c{a};
  return __builtin_bit_cast(__hip_bfloat16, (unsigned short)((c.u + 0x8000u) >> 16));
}
__device__ __forceinline__ unsigned pk_rta(float a, float b) {
  union { float f; unsigned u; } ca{a}, cb{b};
  return ((ca.u + 0x8000u) >> 16) | ((cb.u + 0x8000u) & 0xFFFF0000u);
}
// pack two floats with the SAME rounding prep used (__float2bfloat16/RTNE)
__device__ __forceinline__ unsigned pk_bf(float a, float b) {
  const unsigned short ua =
      __builtin_bit_cast(unsigned short, __float2bfloat16(a));
  const unsigned short ub =
      __builtin_bit_cast(unsigned short, __float2bfloat16(b));
  return (unsigned)ua | ((unsigned)ub << 16);
}
__device__ __forceinline__ float bf_hi(unsigned u) {          // element 1 of pair
  return __builtin_bit_cast(float, u & 0xFFFF0000u);
}
__device__ __forceinline__ float bf_lo(unsigned u) {          // element 0 of pair
  return __builtin_bit_cast(float, u << 16);
}

// ---------------------------------------------------------------------------
// Merged prep (weights only): conversions/transposes + scaled qkv bias.
// ---------------------------------------------------------------------------
#define PN_WP  (128 * 128)
#define PN_QW  (6 * 384 * 128)
#define PN_QB  (6 * 384)
#define PN_OW  (6 * 128 * 128)
#define PN_W1  (6 * 128 * 512)
#define PN_W2  (6 * 512 * 128)
#define QB1 PN_WP
#define QB2 (QB1 + PN_QW)
#define QB3 (QB2 + PN_QB)
#define QB4 (QB3 + PN_OW)
#define QB5 (QB4 + PN_W1)
#define QB6 (QB5 + PN_W2)

__global__ __launch_bounds__(256) void prep_kernel(
    const float* __restrict__ Wp, __hip_bfloat16* __restrict__ wp_t,
    const float* __restrict__ qkv_w, __hip_bfloat16* __restrict__ qkvw,
    const float* __restrict__ qkv_b, float* __restrict__ qb_s,
    const float* __restrict__ out_w, __hip_bfloat16* __restrict__ outw,
    const float* __restrict__ ffn_w1, __hip_bfloat16* __restrict__ w1t,
    const float* __restrict__ ffn_w2, __hip_bfloat16* __restrict__ w2t)
{
  const int idx = blockIdx.x * 256 + threadIdx.x;
  if (idx < QB1) {
    const int i = idx;
    const int c = i >> 7, r = i & 127;
    wp_t[i] = f2bf(Wp[r * 128 + c]);
  } else if (idx < QB2) {
    const int i = idx - QB1;
    const int row = (i >> 7) % 384;
    qkvw[i] = f2bf(qkv_w[i] * ((row < 128) ? QSCALE : 1.f));
  } else if (idx < QB3) {
    const int i = idx - QB2;
    qb_s[i] = qkv_b[i] * (((i % 384) < 128) ? QSCALE : 1.f);
  } else if (idx < QB4) {
    const int i = idx - QB3;
    outw[i] = f2bf(out_w[i]);
  } else if (idx < QB5) {
    const int i = idx - QB4;                 // [l][c][r], R=128, C=512
    const int l = i >> 16, j = i & 65535;
    const int c = j >> 7, r = j & 127;
    w1t[i] = f2bf(ffn_w1[l * 65536 + r * 512 + c]);
  } else if (idx < QB6) {
    const int i = idx - QB5;                 // [l][c][r], R=512, C=128
    const int l = i >> 16, j = i & 65535;
    const int c = j >> 9, r = j & 511;
    w2t[i] = f2bf(ffn_w2[l * 65536 + r * 128 + c]);
  }
}

// ---------------------------------------------------------------------------
// gemm_in: input projection with f32 A staged directly (R29, unchanged).
// ---------------------------------------------------------------------------
__global__ __launch_bounds__(256) void gemm_in(
    const float* __restrict__ A,             // [M][128] f32
    const __hip_bfloat16* __restrict__ B,    // [128 n][128 k] bf16
    const float* __restrict__ bias,
    __hip_bfloat16* __restrict__ outb)
{
  __shared__ __align__(16) __hip_bfloat16 As[64 * 136];
  __shared__ __align__(16) __hip_bfloat16 Bs[128 * 136];

  const int tid = threadIdx.x;
  const int m0 = blockIdx.x << 6;
  const int wave = tid >> 6;
  const int lane = tid & 63;
  const int quad = lane >> 4;
  const int l15 = lane & 15;
  const int wrow = wave * 16;

  f32x4 acc[8];
#pragma unroll
  for (int ni = 0; ni < 8; ++ni) acc[ni] = (f32x4){0.f, 0.f, 0.f, 0.f};

#pragma unroll
  for (int p = 0; p < 4; ++p) {
    const int e = tid + (p << 8);
    const int row = e >> 4;
    const int c = e & 15;
    const float4 fa = *(const float4*)(A + (size_t)(m0 + row) * 128 + c * 8);
    const float4 fb = *(const float4*)(A + (size_t)(m0 + row) * 128 + c * 8 + 4);
    uint4 u;
    u.x = pk_bf(fa.x, fa.y);
    u.y = pk_bf(fa.z, fa.w);
    u.z = pk_bf(fb.x, fb.y);
    u.w = pk_bf(fb.z, fb.w);
    *(uint4*)&As[row * 136 + c * 8] = u;
  }
#pragma unroll
  for (int p = 0; p < 8; ++p) {
    const int e = tid + (p << 8);
    const int row = e >> 4;
    const int c = e & 15;
    *(uint4*)&Bs[row * 136 + c * 8] =
        *(const uint4*)(B + (size_t)row * 128 + c * 8);
  }
  __syncthreads();

#pragma unroll
  for (int ks = 0; ks < 4; ++ks) {
    const bf16x8 af = *(const bf16x8*)&As[(wrow + l15) * 136 + ks * 32 + quad * 8];
#pragma unroll
    for (int ni = 0; ni < 8; ++ni) {
      const bf16x8 bfr =
          *(const bf16x8*)&Bs[(ni * 16 + l15) * 136 + ks * 32 + quad * 8];
      acc[ni] = __builtin_amdgcn_mfma_f32_16x16x32_bf16(af, bfr, acc[ni], 0, 0, 0);
    }
  }

#pragma unroll
  for (int ni = 0; ni < 8; ++ni) {
    const int cl = ni * 16 + l15;
    const float bv = bias[cl];
#pragma unroll
    for (int r = 0; r < 4; ++r) {
      outb[(size_t)(m0 + wrow + quad * 4 + r) * 128 + cl] =
          bf_rta(acc[ni][r] + bv);
    }
  }
}

// ---------------------------------------------------------------------------
// Fused outproj + residual + LN1 + FFN + residual + LN2 (+ optional pooling
// partials on the final layer: per-wave 128-float rows, written once).
// ---------------------------------------------------------------------------
__global__ __launch_bounds__(256) void oproj_ffn(
    const __hip_bfloat16* __restrict__ ab,   // attn output (A of outproj)
    __hip_bfloat16* __restrict__ hb,         // residual in, final out
    const __hip_bfloat16* __restrict__ ow,   // layer [128 n][128 k] bf16
    const float* __restrict__ ob,
    const float* __restrict__ ln1g, const float* __restrict__ ln1b,
    const __hip_bfloat16* __restrict__ w1,   // layer [512 n][128 k] bf16
    const __hip_bfloat16* __restrict__ w2,   // layer [128 n][512 k] bf16
    const float* __restrict__ fb1, const float* __restrict__ fb2,
    const float* __restrict__ ln2g, const float* __restrict__ ln2b,
    float* __restrict__ pool_part)           // null except last layer
{
  __shared__ __align__(16) __hip_bfloat16 AF[64 * 136];   // A / h1 / F
  __shared__ __align__(16) __hip_bfloat16 Bs[128 * 136];  // ow / W1c / W2c

  const int tid = threadIdx.x;
  const int m0 = blockIdx.x << 6;
  const int wave = tid >> 6;
  const int lane = tid & 63;
  const int quad = lane >> 4;
  const int l15 = lane & 15;
  const int wrow = wave * 16;
  const int node = m0 + wrow + l15;        // this lane's node (transposed lyt)
  const int ch0 = quad * 4;                // channel base within each ni group

  // ---- early residual load: 8x uint2; latency hides under staging+GEMM ----
  uint2 hres[8];
#pragma unroll
  for (int ni = 0; ni < 8; ++ni)
    hres[ni] = *(const uint2*)(hb + (size_t)node * 128 + ni * 16 + ch0);

  // ---- stage attnb tile (64x128) and ow (128x128) ----
#pragma unroll
  for (int p = 0; p < 4; ++p) {
    const int e = tid + (p << 8);
    const int row = e >> 4, c = e & 15;
    *(uint4*)&AF[row * 136 + c * 8] =
        *(const uint4*)(ab + (size_t)(m0 + row) * 128 + c * 8);
  }
#pragma unroll
  for (int p = 0; p < 8; ++p) {
    const int e = tid + (p << 8);
    const int row = e >> 4, c = e & 15;
    *(uint4*)&Bs[row * 136 + c * 8] =
        *(const uint4*)(ow + (size_t)row * 128 + c * 8);
  }
  __syncthreads();

  // attnb frags (node rows; usable as B-operand = A^T)
  bf16x8 af[4];
#pragma unroll
  for (int ks = 0; ks < 4; ++ks)
    af[ks] = *(const bf16x8*)&AF[(wrow + l15) * 136 + ks * 32 + quad * 8];

  // ---- outproj, transposed: acc[ni][r] = O[ch = ni*16+ch0+r][node] ----
  f32x4 acc[8];
#pragma unroll
  for (int ni = 0; ni < 8; ++ni) acc[ni] = (f32x4){0.f, 0.f, 0.f, 0.f};
#pragma unroll
  for (int ks = 0; ks < 4; ++ks)
#pragma unroll
    for (int ni = 0; ni < 8; ++ni) {
      const bf16x8 bfr =
          *(const bf16x8*)&Bs[(ni * 16 + l15) * 136 + ks * 32 + quad * 8];
      acc[ni] = __builtin_amdgcn_mfma_f32_16x16x32_bf16(bfr, af[ks], acc[ni], 0, 0, 0);
    }

  // ---- residual + LN1 (cross-quad reduce); h1 -> AF wave-private rows ----
  {
    float s = 0.f, sq = 0.f;
#pragma unroll
    for (int ni = 0; ni < 8; ++ni) {
      const f32x4 obv = *(const f32x4*)(ob + ni * 16 + ch0);
#pragma unroll
      for (int r = 0; r < 4; ++r) {
        const unsigned hu = (r & 2) ? hres[ni].y : hres[ni].x;
        const float hv = (r & 1) ? bf_hi(hu) : bf_lo(hu);
        const float v = acc[ni][r] + obv[r] + hv;
        acc[ni][r] = v;
        s += v;
        sq += v * v;
      }
    }
    s += __shfl_xor(s, 16, 64);  sq += __shfl_xor(sq, 16, 64);
    s += __shfl_xor(s, 32, 64);  sq += __shfl_xor(sq, 32, 64);
    const float mean = s * (1.f / 128.f);
    const float rs = rsqrtf(sq * (1.f / 128.f) - mean * mean + 1e-5f);
#pragma unroll
    for (int ni = 0; ni < 8; ++ni) {
      const f32x4 gv = *(const f32x4*)(ln1g + ni * 16 + ch0);
      const f32x4 bv = *(const f32x4*)(ln1b + ni * 16 + ch0);
      const float o0 = (acc[ni][0] - mean) * rs * gv[0] + bv[0];
      const float o1 = (acc[ni][1] - mean) * rs * gv[1] + bv[1];
      const float o2 = (acc[ni][2] - mean) * rs * gv[2] + bv[2];
      const float o3 = (acc[ni][3] - mean) * rs * gv[3] + bv[3];
      const uint2 pk = make_uint2(pk_rta(o0, o1), pk_rta(o2, o3));
      hres[ni] = pk;   // bf16 h1 for the LN2 residual (bit-exact vs AF copy)
      *(uint2*)&AF[(wrow + l15) * 136 + ni * 16 + ch0] = pk;
    }
  }

  // ---- FFN ----
  __syncthreads();   // all waves done reading ow from Bs
#pragma unroll
  for (int p = 0; p < 8; ++p) {     // stage W1 chunk 0
    const int e = tid + (p << 8);
    const int row = e >> 4, cc = e & 15;
    *(uint4*)&Bs[row * 136 + cc * 8] =
        *(const uint4*)(w1 + (size_t)row * 128 + cc * 8);
  }
  // h1 frags from AF (in-wave ordering vs this wave's LN writes)
  bf16x8 hf[4];
#pragma unroll
  for (int ks = 0; ks < 4; ++ks)
    hf[ks] = *(const bf16x8*)&AF[(wrow + l15) * 136 + ks * 32 + quad * 8];
  __syncthreads();   // W1c0 staged

  f32x4 facc[8];
#pragma unroll
  for (int ni = 0; ni < 8; ++ni) facc[ni] = (f32x4){0.f, 0.f, 0.f, 0.f};

  for (int c = 0; c < 4; ++c) {
    if (c > 0) {
      __syncthreads();   // W2 reads of previous chunk complete
#pragma unroll
      for (int p = 0; p < 8; ++p) {
        const int e = tid + (p << 8);
        const int row = e >> 4, cc = e & 15;
        *(uint4*)&Bs[row * 136 + cc * 8] =
            *(const uint4*)(w1 + (size_t)(c * 128 + row) * 128 + cc * 8);
      }
      __syncthreads();
    }

    // ---- F chunk, transposed: fc[ni] = F[n1 = ni*16+ch0+r][node] ----
    f32x4 fc[8];
#pragma unroll
    for (int ni = 0; ni < 8; ++ni) fc[ni] = (f32x4){0.f, 0.f, 0.f, 0.f};
#pragma unroll
    for (int ks = 0; ks < 4; ++ks)
#pragma unroll
      for (int ni = 0; ni < 8; ++ni) {
        const bf16x8 wf =
            *(const bf16x8*)&Bs[(ni * 16 + l15) * 136 + ks * 32 + quad * 8];
        fc[ni] = __builtin_amdgcn_mfma_f32_16x16x32_bf16(wf, hf[ks], fc[ni], 0, 0, 0);
      }
    // bias + relu + pack into AF[node row][n1 = ni*16 + ch0 + r]
#pragma unroll
    for (int ni = 0; ni < 8; ++ni) {
      const f32x4 bv = *(const f32x4*)(fb1 + c * 128 + ni * 16 + ch0);
      const float v0 = fmaxf(fc[ni][0] + bv[0], 0.f);
      const float v1 = fmaxf(fc[ni][1] + bv[1], 0.f);
      const float v2 = fmaxf(fc[ni][2] + bv[2], 0.f);
      const float v3 = fmaxf(fc[ni][3] + bv[3], 0.f);
      *(uint2*)&AF[(wrow + l15) * 136 + ni * 16 + ch0] =
          make_uint2(pk_rta(v0, v1), pk_rta(v2, v3));
    }
    __syncthreads();   // all waves done reading W1c from Bs

    // ---- stage W2 chunk c (k = c*128 .. +128 of [128][512]) ----
#pragma unroll
    for (int p = 0; p < 8; ++p) {
      const int e = tid + (p << 8);
      const int row = e >> 4, cc = e & 15;
      *(uint4*)&Bs[row * 136 + cc * 8] =
          *(const uint4*)(w2 + (size_t)row * 512 + c * 128 + cc * 8);
    }
    __syncthreads();

    // ---- out += W2_c @ F_c, transposed: facc[ni][r] = out[ch][node] ----
#pragma unroll
    for (int ks2 = 0; ks2 < 4; ++ks2) {
      const bf16x8 ff =
          *(const bf16x8*)&AF[(wrow + l15) * 136 + ks2 * 32 + quad * 8];
#pragma unroll
      for (int ni = 0; ni < 8; ++ni) {
        const bf16x8 wf =
            *(const bf16x8*)&Bs[(ni * 16 + l15) * 136 + ks2 * 32 + quad * 8];
        facc[ni] = __builtin_amdgcn_mfma_f32_16x16x32_bf16(wf, ff, facc[ni], 0, 0, 0);
      }
    }
  }

  // ---- final residual (hres regs) + LN2 -> hb, vectorized stores ----
  {
    float s = 0.f, sq = 0.f;
#pragma unroll
    for (int ni = 0; ni < 8; ++ni) {
      const f32x4 b2v = *(const f32x4*)(fb2 + ni * 16 + ch0);
#pragma unroll
      for (int r = 0; r < 4; ++r) {
        const unsigned hu = (r & 2) ? hres[ni].y : hres[ni].x;
        const float hv = (r & 1) ? bf_hi(hu) : bf_lo(hu);
        const float v = facc[ni][r] + b2v[r] + hv;
        facc[ni][r] = v;
        s += v;
        sq += v * v;
      }
    }
    s += __shfl_xor(s, 16, 64);  sq += __shfl_xor(sq, 16, 64);
    s += __shfl_xor(s, 32, 64);  sq += __shfl_xor(sq, 32, 64);
    const float mean = s * (1.f / 128.f);
    const float rs = rsqrtf(sq * (1.f / 128.f) - mean * mean + 1e-5f);
#pragma unroll
    for (int ni = 0; ni < 8; ++ni) {
      const f32x4 gv = *(const f32x4*)(ln2g + ni * 16 + ch0);
      const f32x4 bv = *(const f32x4*)(ln2b + ni * 16 + ch0);
      const float o0 = (facc[ni][0] - mean) * rs * gv[0] + bv[0];
      const float o1 = (facc[ni][1] - mean) * rs * gv[1] + bv[1];
      const float o2 = (facc[ni][2] - mean) * rs * gv[2] + bv[2];
      const float o3 = (facc[ni][3] - mean) * rs * gv[3] + bv[3];
      facc[ni][0] = o0; facc[ni][1] = o1;   // keep f32 LN2 output for pooling
      facc[ni][2] = o2; facc[ni][3] = o3;
      *(uint2*)(hb + (size_t)node * 128 + ni * 16 + ch0) =
          make_uint2(pk_rta(o0, o1), pk_rta(o2, o3));
    }
  }

  // ---- optional: per-wave pooling partials (final layer only) ----
  // Reduce each channel over the wave's 16 nodes (lanes differing in l15
  // bits), then lanes l15==0 write their 32 channels. Each slot written once.
  if (pool_part != nullptr) {
    float* prow = pool_part + (size_t)(blockIdx.x * 4 + wave) * 128;
#pragma unroll
    for (int ni = 0; ni < 8; ++ni) {
#pragma unroll
      for (int r = 0; r < 4; ++r) {
        float v = facc[ni][r];
        v += __shfl_xor(v, 1, 64);
        v += __shfl_xor(v, 2, 64);
        v += __shfl_xor(v, 4, 64);
        v += __shfl_xor(v, 8, 64);
        if (l15 == 0) prow[ni * 16 + ch0 + r] = v;
      }
    }
  }
}

// ---------------------------------------------------------------------------
// Fused QKV + flash attention (R19, byte-identical): P stride 40, single
// buffer, PQ[8][1536], two-stage (kt,s) st prefetch.
// ---------------------------------------------------------------------------
__global__ __launch_bounds__(512) void attn_kernel(
    const __hip_bfloat16* __restrict__ hbf,
    const __hip_bfloat16* __restrict__ qkvw_l,
    const float* __restrict__ qb_l,
    __hip_bfloat16* __restrict__ o)
{
  __shared__ __align__(16) __hip_bfloat16 Ks[512 * 24];
  __shared__ __align__(16) __hip_bfloat16 Vt[16 * 520];
  __shared__ __align__(16) __hip_bfloat16 PQ[8][1536];

  const int tid = threadIdx.x;
  const int b = blockIdx.x & 63;        // XCD-aware: graph in low bits
  const int hh = blockIdx.x >> 6;
  const __hip_bfloat16* hrow = hbf + (size_t)b * 512 * 128;

  const int wave = tid >> 6;
  const int lane = tid & 63;
  const int l31 = lane & 31;
  const int l5 = lane >> 5;
  const int l15 = lane & 15;
  const int quad = lane >> 4;
  const int q0 = wave * 64;

  {
    f32x4 qacc[4], kacc[4], vacc[4];
#pragma unroll
    for (int mt = 0; mt < 4; ++mt) {
      qacc[mt] = (f32x4){0.f, 0.f, 0.f, 0.f};
      kacc[mt] = (f32x4){0.f, 0.f, 0.f, 0.f};
      vacc[mt] = (f32x4){0.f, 0.f, 0.f, 0.f};
    }
#pragma unroll
    for (int ks = 0; ks < 4; ++ks) {
      const int kc = ks * 32 + quad * 8;
      const bf16x8 wq = *(const bf16x8*)(qkvw_l + (size_t)(hh * 16 + l15) * 128 + kc);
      const bf16x8 wk = *(const bf16x8*)(qkvw_l + (size_t)(128 + hh * 16 + l15) * 128 + kc);
      const bf16x8 wv = *(const bf16x8*)(qkvw_l + (size_t)(256 + hh * 16 + l15) * 128 + kc);
#pragma unroll
      for (int mt = 0; mt < 4; ++mt) {
        const bf16x8 hf =
            *(const bf16x8*)(hrow + (size_t)(q0 + mt * 16 + l15) * 128 + kc);
        qacc[mt] = __builtin_amdgcn_mfma_f32_16x16x32_bf16(hf, wq, qacc[mt], 0, 0, 0);
        kacc[mt] = __builtin_amdgcn_mfma_f32_16x16x32_bf16(hf, wk, kacc[mt], 0, 0, 0);
        vacc[mt] = __builtin_amdgcn_mfma_f32_16x16x32_bf16(wv, hf, vacc[mt], 0, 0, 0);
      }
    }
    const float qb = qb_l[hh * 16 + l15];
    const float kb = qb_l[128 + hh * 16 + l15];
    const f32x4 vb = *(const f32x4*)(qb_l + 256 + hh * 16 + quad * 4);
#pragma unroll
    for (int mt = 0; mt < 4; ++mt)
#pragma unroll
      for (int r = 0; r < 4; ++r) {
        const int nd = mt * 16 + quad * 4 + r;
        PQ[wave][nd * 24 + l15] = bf_rta(qacc[mt][r] + qb);
        Ks[(q0 + nd) * 24 + l15] = bf_rta(kacc[mt][r] + kb);
        Vt[(quad * 4 + r) * 520 + q0 + mt * 16 + l15] = bf_rta(vacc[mt][r] + vb[r]);
      }
  }

  bf16x8 qf[2];
#pragma unroll
  for (int s = 0; s < 2; ++s)
    qf[s] = *(const bf16x8*)&PQ[wave][(s * 32 + l31) * 24 + l5 * 8];
  __syncthreads();

  __hip_bfloat16* Pw = &PQ[wave][0];
  const f32x16 z16 = {};
  f32x4 oacc[2][2];
#pragma unroll
  for (int s = 0; s < 2; ++s) { oacc[s][0] = (f32x4){0.f,0.f,0.f,0.f};
                                oacc[s][1] = (f32x4){0.f,0.f,0.f,0.f}; }
  float lacc[2] = {0.f, 0.f};

  // ---- pipeline prologue: kf and st for step (kt=0, s=0) ----
  bf16x8 kf = *(const bf16x8*)&Ks[(0 * 32 + l31) * 24 + l5 * 8];
  f32x16 st0 = __builtin_amdgcn_mfma_f32_32x32x16_bf16(kf, qf[0], z16, 0, 0, 0);

  for (int kt = 0; kt < 16; ++kt) {
    const bf16x8 vf = *(const bf16x8*)&Vt[l15 * 520 + kt * 32 + quad * 8];

    // ================= step (kt, s=0): uses st0 (computed a step ago) ====
    {
      float pr[16];
#pragma unroll
      for (int r = 0; r < 16; ++r) pr[r] = FAST_EXP2(st0[r]);
      const float a0 = (pr[0] + pr[1]) + (pr[2] + pr[3]);
      const float a1 = (pr[4] + pr[5]) + (pr[6] + pr[7]);
      const float a2 = (pr[8] + pr[9]) + (pr[10] + pr[11]);
      const float a3 = (pr[12] + pr[13]) + (pr[14] + pr[15]);
      lacc[0] += (a0 + a1) + (a2 + a3);
#pragma unroll
      for (int g = 0; g < 4; ++g) {
        *(uint2*)&Pw[l31 * 40 + g * 8 + l5 * 4] =
            make_uint2(pk_rta(pr[g * 4 + 0], pr[g * 4 + 1]),
                       pk_rta(pr[g * 4 + 2], pr[g * 4 + 3]));
      }
    }
    // next step's QK^T (s=1, same kf) — hides P write->read turnaround
    f32x16 st1 = __builtin_amdgcn_mfma_f32_32x32x16_bf16(kf, qf[1], z16, 0, 0, 0);
#pragma unroll
    for (int g = 0; g < 2; ++g) {
      const bf16x8 pf = *(const bf16x8*)&Pw[(g * 16 + l15) * 40 + quad * 8];
      oacc[0][g] = __builtin_amdgcn_mfma_f32_16x16x32_bf16(vf, pf, oacc[0][g], 0, 0, 0);
    }

    // ================= step (kt, s=1): uses st1 =========================
    {
      float pr[16];
#pragma unroll
      for (int r = 0; r < 16; ++r) pr[r] = FAST_EXP2(st1[r]);
      const float a0 = (pr[0] + pr[1]) + (pr[2] + pr[3]);
      const float a1 = (pr[4] + pr[5]) + (pr[6] + pr[7]);
      const float a2 = (pr[8] + pr[9]) + (pr[10] + pr[11]);
      const float a3 = (pr[12] + pr[13]) + (pr[14] + pr[15]);
      lacc[1] += (a0 + a1) + (a2 + a3);
#pragma unroll
      for (int g = 0; g < 4; ++g) {
        *(uint2*)&Pw[l31 * 40 + g * 8 + l5 * 4] =
            make_uint2(pk_rta(pr[g * 4 + 0], pr[g * 4 + 1]),
                       pk_rta(pr[g * 4 + 2], pr[g * 4 + 3]));
      }
    }
    // next kt's kf load + QK^T (s=0) — hides P write->read turnaround
    if (kt < 15) {
      kf = *(const bf16x8*)&Ks[((kt + 1) * 32 + l31) * 24 + l5 * 8];
      st0 = __builtin_amdgcn_mfma_f32_32x32x16_bf16(kf, qf[0], z16, 0, 0, 0);
    }
#pragma unroll
    for (int g = 0; g < 2; ++g) {
      const bf16x8 pf = *(const bf16x8*)&Pw[(g * 16 + l15) * 40 + quad * 8];
      oacc[1][g] = __builtin_amdgcn_mfma_f32_16x16x32_bf16(vf, pf, oacc[1][g], 0, 0, 0);
    }
  }

#pragma unroll
  for (int s = 0; s < 2; ++s) {
    const float lv = lacc[s] + __shfl_xor(lacc[s], 32, 64);
#pragma unroll
    for (int g = 0; g < 2; ++g) {
      const float lq = __shfl(lv, g * 16 + l15, 64);
      const float inv = 1.f / lq;
      const int qrow = q0 + s * 32 + g * 16 + l15;
      *(uint2*)(o + ((size_t)b * 512 + qrow) * 128 + hh * 16 + quad * 4) =
          make_uint2(pk_rta(oacc[s][g][0] * inv, oacc[s][g][1] * inv),
                     pk_rta(oacc[s][g][2] * inv, oacc[s][g][3] * inv));
    }
  }
}

// ---------------------------------------------------------------------------
// Head v2: sum 32 per-wave partial rows per graph (1MB total read) + 128->64
// relu -> 64->10. One block per graph.
// ---------------------------------------------------------------------------
__global__ __launch_bounds__(256) void head_kernel(
    const float* __restrict__ part,          // [2048][128] per-wave partials
    const float* __restrict__ w1, const float* __restrict__ b1,
    const float* __restrict__ w2, const float* __restrict__ b2,
    float* __restrict__ out)
{
  __shared__ float pooled[128];
  __shared__ float hid[64];

  const int b = blockIdx.x;
  const int tid = threadIdx.x;

  if (tid < 128) {
    float s = 0.f;
    const float* p = part + (size_t)b * 32 * 128 + tid;
    for (int j = 0; j < 32; ++j) s += p[(size_t)j * 128];
    pooled[tid] = s * (1.f / 512.f);
  }
  __syncthreads();

  if (tid < 64) {
    float a = b1[tid];
    for (int dd = 0; dd < 128; ++dd) a = fmaf(pooled[dd], w1[dd * 64 + tid], a);
    hid[tid] = fmaxf(a, 0.f);
  }
  __syncthreads();

  if (tid < 10) {
    float a = b2[tid];
    for (int j = 0; j < 64; ++j) a = fmaf(hid[j], w2[j * 10 + tid], a);
    out[b * 10 + tid] = a;
  }
}

// ---------------------------------------------------------------------------
extern "C" void kernel_launch(void* const* d_in, const int* in_sizes, int n_in,
                              void* d_out, int out_size, void* d_ws, size_t ws_size,
                              hipStream_t stream)
{
  (void)in_sizes; (void)n_in; (void)out_size; (void)ws_size;

  const float* x      = (const float*)d_in[0];
  const float* Wp     = (const float*)d_in[4];
  const float* bp     = (const float*)d_in[5];
  const float* qkv_w  = (const float*)d_in[6];
  const float* qkv_b  = (const float*)d_in[7];
  const float* out_w  = (const float*)d_in[8];
  const float* out_b  = (const float*)d_in[9];
  const float* ln1_g  = (const float*)d_in[10];
  const float* ln1_b  = (const float*)d_in[11];
  const float* ffn_w1 = (const float*)d_in[12];
  const float* ffn_b1 = (const float*)d_in[13];
  const float* ffn_w2 = (const float*)d_in[14];
  const float* ffn_b2 = (const float*)d_in[15];
  const float* ln2_g  = (const float*)d_in[16];
  const float* ln2_b  = (const float*)d_in[17];
  const float* cw1    = (const float*)d_in[18];
  const float* cb1    = (const float*)d_in[19];
  const float* cw2    = (const float*)d_in[20];
  const float* cb2    = (const float*)d_in[21];

  const int N = NROWS;

  // ws: hbf | free slot (pool partials) | attnb | weights | qb_s
  __hip_bfloat16* hbf   = (__hip_bfloat16*)d_ws;
  __hip_bfloat16* xb    = hbf + (size_t)N * 128;     // reused for pool_part
  __hip_bfloat16* attnb = xb + (size_t)N * 128;
  __hip_bfloat16* wp_t  = attnb + (size_t)N * 128;
  __hip_bfloat16* qkvw  = wp_t + 128 * 128;
  __hip_bfloat16* outw  = qkvw + 6 * 384 * 128;
  __hip_bfloat16* w1t   = outw + 6 * 128 * 128;
  __hip_bfloat16* w2t   = w1t + 6 * 512 * 128;
  float* qb_s = (float*)(w2t + 6 * 128 * 512);
  float* pool_part = (float*)xb;                     // 2048*128 f32 = 1MB

  const dim3 blk(256);

  // ---- merged weight-prep dispatch ----
  prep_kernel<<<dim3((QB6 + 255) / 256), blk, 0, stream>>>(
      Wp, wp_t, qkv_w, qkvw, qkv_b, qb_s, out_w, outw,
      ffn_w1, w1t, ffn_w2, w2t);

  // ---- input projection: hbf = bf16(x @ Wp + bp), f32 A staged directly ----
  gemm_in<<<dim3(N / 64), blk, 0, stream>>>(x, wp_t, bp, hbf);

  for (int i = 0; i < NLAYER; ++i) {
    // fused QKV + attention (XCD-swizzled grid)
    attn_kernel<<<dim3(64 * 8), dim3(512), 0, stream>>>(
        hbf, qkvw + (size_t)i * 384 * 128, qb_s + (size_t)i * 384, attnb);

    // hbf = LN2( h1 + relu(h1@W1+b1)@W2 + b2 ), h1 = LN1(hbf + attnb@ow^T + ob)
    // Final layer also emits per-wave pooling partials.
    oproj_ffn<<<dim3(N / 64), blk, 0, stream>>>(
        attnb, hbf,
        outw + (size_t)i * 128 * 128, out_b + (size_t)i * 128,
        ln1_g + (size_t)i * 128, ln1_b + (size_t)i * 128,
        w1t + (size_t)i * 512 * 128, w2t + (size_t)i * 128 * 512,
        ffn_b1 + (size_t)i * 512, ffn_b2 + (size_t)i * 128,
        ln2_g + (size_t)i * 128, ln2_b + (size_t)i * 128,
        (i == NLAYER - 1) ? pool_part : (float*)nullptr);
  }

  head_kernel<<<dim3(64), blk, 0, stream>>>(pool_part, cw1, cb1, cw2, cb2,
                                            (float*)d_out);
}